// Round 17
// baseline (2540.702 us; speedup 1.0000x reference)
//
#include <hip/hip_runtime.h>
#include <float.h>
#include <math.h>

#define BB 16
#define NN 2048
#define KNNK 20
#define HC 512
#define O5 1024
#define EPSF 1e-5f
#define GBLK 2048   // number of k_gather blocks (= BB*NN/16)

typedef short bf16x8 __attribute__((ext_vector_type(8)));
typedef float f32x4 __attribute__((ext_vector_type(4)));

__device__ __forceinline__ float leakyf(float y){ return y > 0.f ? y : 0.2f*y; }

__device__ __forceinline__ ushort f2bf(float f){
  unsigned u = __float_as_uint(f);
  unsigned r = (u + 0x7fffu + ((u >> 16) & 1u)) >> 16;
  return (ushort)r;
}

// one bitonic compare-exchange step over 64 lanes; order: value desc, index asc
// (hardware-validated R8/R10/R11/R12)
__device__ __forceinline__ void bsort_step(float& v, int& id, int lane, int k, int j){
  float pv = __shfl_xor(v, j, 64);
  int pid = __shfl_xor(id, j, 64);
  bool up = ((lane & k) == 0);
  bool iLow = ((lane & j) == 0);
  bool pBefore = (pv > v) || (pv == v && pid < id);
  if ((up == iLow) ? pBefore : !pBefore){ v = pv; id = pid; }
}

// ---------------- transpose x (B,3,N) -> xP (B,N,4) padded ----------------
__global__ void k_transpose(const float* __restrict__ x, float* __restrict__ xP){
  int gid = blockIdx.x*256 + threadIdx.x;
  if (gid >= BB*NN) return;
  int b = gid / NN, n = gid % NN;
  const float* xb = x + (size_t)b*3*NN;
  *(float4*)&xP[(size_t)gid*4] = make_float4(xb[n], xb[NN + n], xb[2*NN + n], 0.f);
}

// ---------------- squared norms ----------------
__global__ void k_sqn(const float* __restrict__ xin, int xs, int C, float* __restrict__ sqn){
  int gid = blockIdx.x*256 + threadIdx.x;
  if (gid >= BB*NN) return;
  const float* r = xin + (size_t)gid*xs;
  float s = 0.f;
  for (int c = 0; c < C; ++c){ float v = r[c]; s = fmaf(v, v, s); }
  sqn[gid] = s;
}

// ---------------- KNN: 256 thr = 4 waves x RW rows ----------------
// Cold (layer 1, C=3, MC=512, RW=4): extraction + inserts (R16-validated).
// Warm (layers 2-4, MC=256, RW=8): warm-start top-20 from prev layer;
//   coalesced LDS staging of m-points; uniform-scalar query reads.
//   RW=8 doubles fmaf per ds_read_b128 (LDS-pipe-bound per R16 counters).
// Ascending-channel fmaf chains everywhere -> bit-exact -> identical top-20.
template<int C, int MC, int RW, bool WARM>
__global__ __launch_bounds__(256) void k_knn(const float* __restrict__ xin, int xs,
                                             const float* __restrict__ sqn,
                                             const int* __restrict__ idx_prev,
                                             int* __restrict__ idx_out){
  const int TN = 4*RW;
  const int NPL = MC/64;
  const int LNPL = (NPL == 8) ? 3 : 2;
  __shared__ float xnT[WARM ? 1 : 8][20];
  __shared__ float xmT[(C == 3 ? 1 : 16)][MC + 4];
  __shared__ float cval[TN][24];
  __shared__ int   cidx[TN][24];
  __shared__ float sqnn[TN];
  int tid = threadIdx.x;
  int b = (blockIdx.x*TN) / NN, n0 = (blockIdx.x*TN) % NN;
  const float* xb = xin + (size_t)b*NN*xs;

  if constexpr (!WARM){
    for (int e = tid; e < TN*C; e += 256){
      int r = e / C, c = e % C;
      xnT[c][r] = xb[(size_t)(n0+r)*xs + c];
    }
  }
  if (tid < TN) sqnn[tid] = sqn[b*NN + n0 + tid];
  __syncthreads();

  int wid = tid >> 6, lane = tid & 63, r0 = wid*RW;
  float tv[RW]; int ti[RW];

  int urow[RW];
  #pragma unroll
  for (int i = 0; i < RW; ++i) urow[i] = __builtin_amdgcn_readfirstlane(n0 + r0 + i);

  if constexpr (WARM){
    #pragma unroll
    for (int i = 0; i < RW; ++i){
      int r = r0 + i;
      int m = (lane < KNNK) ? idx_prev[(size_t)(b*NN + n0 + r)*KNNK + lane] : 0;
      const float* xq = xb + (size_t)urow[i]*xs;
      const float* xm = xb + (size_t)m*xs;
      float dot = 0.f;
      #pragma unroll 8
      for (int c = 0; c < C; c += 4){
        float4 qv = *(const float4*)(xq + c);
        float4 mv = *(const float4*)(xm + c);
        dot = fmaf(qv.x, mv.x, dot);
        dot = fmaf(qv.y, mv.y, dot);
        dot = fmaf(qv.z, mv.z, dot);
        dot = fmaf(qv.w, mv.w, dot);
      }
      float dval = (lane < KNNK) ? ((2.f*dot - sqnn[r]) - sqn[b*NN + m]) : -FLT_MAX;
      int did = (lane < KNNK) ? m : 0x7fffffff;
      #pragma unroll
      for (int k = 2; k <= 64; k <<= 1)
        #pragma unroll
        for (int jj = k >> 1; jj > 0; jj >>= 1)
          bsort_step(dval, did, lane, k, jj);
      if (lane < KNNK){ cval[r][lane] = dval; cidx[r][lane] = did; }
      tv[i] = __shfl(dval, KNNK-1); ti[i] = __shfl(did, KNNK-1);
    }
    __syncthreads();
  }

  for (int base = 0; base < NN; base += MC){
    float pd[RW][NPL];
    if constexpr (C == 3){
      int m0g = base + lane*NPL;
      const float* xm = xb + (size_t)m0g*4;
      float4 q[NPL];
      #pragma unroll
      for (int j = 0; j < NPL; ++j) q[j] = *(const float4*)&xm[j*4];
      float smr[NPL];
      #pragma unroll
      for (int j = 0; j < NPL; j += 4){
        float4 s4 = *(const float4*)&sqn[b*NN + m0g + j];
        smr[j] = s4.x; smr[j+1] = s4.y; smr[j+2] = s4.z; smr[j+3] = s4.w;
      }
      #pragma unroll
      for (int i = 0; i < RW; ++i){
        float a0 = xnT[0][r0+i], a1 = xnT[1][r0+i], a2 = xnT[2][r0+i], sq = sqnn[r0+i];
        #pragma unroll
        for (int j = 0; j < NPL; ++j){
          float d = a0*q[j].x; d = fmaf(a1, q[j].y, d); d = fmaf(a2, q[j].z, d);
          pd[i][j] = (2.f*d - sq) - smr[j];
        }
      }
    } else {
      // COALESCED LDS staging (R14-validated): 4 threads/point, 64B contiguous segs
      float acc[RW][4];
      #pragma unroll
      for (int i = 0; i < RW; ++i)
        #pragma unroll
        for (int p = 0; p < 4; ++p) acc[i][p] = 0.f;
      int pm = tid >> 2, fq = tid & 3;
      for (int c0 = 0; c0 < C; c0 += 16){
        #pragma unroll
        for (int p = 0; p < MC/64; ++p){
          int pt = p*64 + pm;
          float4 vv = *(const float4*)(xb + (size_t)(base + pt)*xs + c0 + fq*4);
          xmT[fq*4+0][pt] = vv.x; xmT[fq*4+1][pt] = vv.y;
          xmT[fq*4+2][pt] = vv.z; xmT[fq*4+3][pt] = vv.w;
        }
        __syncthreads();
        #pragma unroll
        for (int cc4 = 0; cc4 < 16; cc4 += 4){
          float aq[RW][4];
          #pragma unroll
          for (int i = 0; i < RW; ++i)
            *(float4*)&aq[i][0] = *(const float4*)(xb + (size_t)urow[i]*xs + c0 + cc4);
          #pragma unroll
          for (int dc = 0; dc < 4; ++dc){
            float4 m4 = *(const float4*)&xmT[cc4+dc][lane*4];
            float mv[4] = {m4.x, m4.y, m4.z, m4.w};
            #pragma unroll
            for (int i = 0; i < RW; ++i)
              #pragma unroll
              for (int p = 0; p < 4; ++p)
                acc[i][p] = fmaf(aq[i][dc], mv[p], acc[i][p]);
          }
        }
        __syncthreads();
      }
      float4 sm4 = *(const float4*)&sqn[b*NN + base + lane*4];
      float smr[4] = {sm4.x, sm4.y, sm4.z, sm4.w};
      #pragma unroll
      for (int i = 0; i < RW; ++i){
        float sq = sqnn[r0+i];
        #pragma unroll
        for (int j = 0; j < 4; ++j)
          pd[i][j] = (2.f*acc[i][j] - sq) - smr[j];
      }
    }

    bool handled = false;
    if constexpr (!WARM){
      if (base == 0){
        handled = true;
        // interleaved sorted top-20 extraction (RW rows together), NPL-generic
        float lv[RW]; int li[RW];
        #pragma unroll
        for (int i = 0; i < RW; ++i){
          float v0 = pd[i][0]; int j0 = 0;
          #pragma unroll
          for (int j = 1; j < NPL; ++j) if (pd[i][j] > v0){ v0 = pd[i][j]; j0 = j; }
          lv[i] = v0; li[i] = lane*NPL + j0;
        }
        float bv[RW]; int bi[RW];
        for (int it = 0; it < KNNK; ++it){
          #pragma unroll
          for (int i = 0; i < RW; ++i){ bv[i] = lv[i]; bi[i] = li[i]; }
          #pragma unroll
          for (int off = 1; off < 64; off <<= 1){
            #pragma unroll
            for (int i = 0; i < RW; ++i){
              float ov = __shfl_xor(bv[i], off, 64);
              int oi = __shfl_xor(bi[i], off, 64);
              if (ov > bv[i] || (ov == bv[i] && oi < bi[i])){ bv[i] = ov; bi[i] = oi; }
            }
          }
          #pragma unroll
          for (int i = 0; i < RW; ++i){
            if (lane == it){ cval[r0+i][it] = bv[i]; cidx[r0+i][it] = bi[i]; }
            int wl = bi[i] >> LNPL, wj = bi[i] & (NPL - 1);
            if (lane == wl){
              #pragma unroll
              for (int j = 0; j < NPL; ++j) if (j == wj) pd[i][j] = -FLT_MAX;
              float v0 = pd[i][0]; int j0 = 0;
              #pragma unroll
              for (int j = 1; j < NPL; ++j) if (pd[i][j] > v0){ v0 = pd[i][j]; j0 = j; }
              lv[i] = v0; li[i] = lane*NPL + j0;
            }
          }
        }
        #pragma unroll
        for (int i = 0; i < RW; ++i){ tv[i] = bv[i]; ti[i] = bi[i]; }
      }
    }
    if (!handled){
      #pragma unroll
      for (int i = 0; i < RW; ++i){
        int r = r0 + i;
        bool pred = false;
        #pragma unroll
        for (int j = 0; j < NPL; ++j){
          int ci = base + lane*NPL + j;
          pred = pred || (pd[i][j] > tv[i]) || (pd[i][j] == tv[i] && ci < ti[i]);
        }
        unsigned long long mask = __ballot(pred);
        while (mask){
          int l = __builtin_ctzll(mask); mask &= (mask - 1);
          float cvv[NPL];
          #pragma unroll
          for (int j = 0; j < NPL; ++j) cvv[j] = __shfl(pd[i][j], l);
          #pragma unroll
          for (int j = 0; j < NPL; ++j){
            float cv = cvv[j];
            int ci = base + l*NPL + j;
            if (cv > tv[i] || (cv == tv[i] && ci < ti[i])){
              bool skip = false;
              if constexpr (WARM){
                skip = __ballot((lane < KNNK) && (cidx[r][lane] == ci)) != 0ull;
              }
              if (!skip){
                float ev = -FLT_MAX; int ei = 0x7fffffff;
                if (lane < KNNK){ ev = cval[r][lane]; ei = cidx[r][lane]; }
                bool ahead = (lane < KNNK) && (ev > cv || (ev == cv && ei < ci));
                int pos = __popcll(__ballot(ahead));
                float pev = __shfl_up(ev, 1);
                int   pei = __shfl_up(ei, 1);
                float nv; int ni;
                if (lane < pos){ nv = ev; ni = ei; }
                else if (lane == pos){ nv = cv; ni = ci; }
                else { nv = pev; ni = pei; }
                if (lane < KNNK){ cval[r][lane] = nv; cidx[r][lane] = ni; }
                tv[i] = __shfl(nv, 19); ti[i] = __shfl(ni, 19);
              }
            }
          }
        }
      }
    }
  }

  if (lane < KNNK){
    #pragma unroll
    for (int i = 0; i < RW; ++i){
      int r = r0 + i;
      idx_out[(size_t)(b*NN + n0 + r)*KNNK + lane] = cidx[r][lane];
    }
  }
}

// ---------------- weight prep ----------------
__global__ void k_wprep(const float* __restrict__ W, int O, int C,
                        float* __restrict__ wu, float* __restrict__ wv){
  int i = blockIdx.x*256 + threadIdx.x;
  if (i >= O*C) return;
  int o = i / C, c = i % C;
  float a = W[(size_t)o*2*C + c], b = W[(size_t)o*2*C + C + c];
  wu[i] = a; wv[i] = b - a;
}

// ---------------- u,v GEMM ----------------
__global__ __launch_bounds__(256) void k_uv(const float* __restrict__ xin, int xs, int C,
                                            const float* __restrict__ wu, const float* __restrict__ wv,
                                            int O, float* __restrict__ u, float* __restrict__ v){
  __shared__ float xsh[16][68];
  __shared__ float wush[16][68], wvsh[16][68];
  int tid = threadIdx.x;
  int rb = blockIdx.x*64, ob = blockIdx.y*64;
  int otx = tid % 16, rty = tid / 16;
  float au[4][4] = {}, av[4][4] = {};
  for (int c0 = 0; c0 < C; c0 += 16){
    #pragma unroll
    for (int i = 0; i < 4; ++i){
      int c = otx, r = rty*4 + i;
      xsh[c][r]  = (c0 + c < C) ? xin[(size_t)(rb+r)*xs + c0 + c] : 0.f;
      wush[c][r] = (c0 + c < C) ? wu[(size_t)(ob+r)*C + c0 + c] : 0.f;
      wvsh[c][r] = (c0 + c < C) ? wv[(size_t)(ob+r)*C + c0 + c] : 0.f;
    }
    __syncthreads();
    #pragma unroll
    for (int c = 0; c < 16; ++c){
      float4 xr = *(const float4*)&xsh[c][rty*4];
      float4 wa = *(const float4*)&wush[c][otx*4];
      float4 wb = *(const float4*)&wvsh[c][otx*4];
      float xv[4] = {xr.x, xr.y, xr.z, xr.w};
      float wav[4] = {wa.x, wa.y, wa.z, wa.w};
      float wbv[4] = {wb.x, wb.y, wb.z, wb.w};
      #pragma unroll
      for (int i = 0; i < 4; ++i)
        #pragma unroll
        for (int j = 0; j < 4; ++j){
          au[i][j] = fmaf(xv[i], wav[j], au[i][j]);
          av[i][j] = fmaf(xv[i], wbv[j], av[i][j]);
        }
    }
    __syncthreads();
  }
  #pragma unroll
  for (int i = 0; i < 4; ++i){
    size_t r = (size_t)(rb + rty*4 + i);
    *(float4*)&u[r*O + ob + otx*4] = make_float4(au[i][0], au[i][1], au[i][2], au[i][3]);
    *(float4*)&v[r*O + ob + otx*4] = make_float4(av[i][0], av[i][1], av[i][2], av[i][3]);
  }
}

// ---------------- gather + max/sum/sumsq -> deterministic partials ----------------
__global__ __launch_bounds__(256) void k_gather(const float* __restrict__ u, const float* __restrict__ v,
                                                const int* __restrict__ idx, int O,
                                                float* __restrict__ s,
                                                float* __restrict__ gp1, float* __restrict__ gp2){
  __shared__ float r1[256], r2[256];
  int tid = threadIdx.x;
  int Ppar = 256 / O;
  int o = tid % O, g = tid / O;
  int p0 = blockIdx.x*16;
  float cs = 0.f, cs2 = 0.f;
  int IT = 16 / Ppar;
  for (int it = 0; it < IT; ++it){
    int pi = p0 + it*Ppar + g;
    int b = pi / NN;
    const int* il = idx + (size_t)pi*KNNK;
    float vv = v[(size_t)pi*O + o];
    float mx = -FLT_MAX, su = 0.f, su2 = 0.f;
    #pragma unroll
    for (int k = 0; k < KNNK; ++k){
      int m = il[k];
      float um = u[((size_t)b*NN + m)*O + o];
      mx = fmaxf(mx, um); su += um; su2 = fmaf(um, um, su2);
    }
    s[(size_t)pi*O + o] = mx + vv;
    cs += su + (float)KNNK*vv;
    cs2 += su2 + 2.f*vv*su + (float)KNNK*vv*vv;
  }
  r1[tid] = cs; r2[tid] = cs2;
  __syncthreads();
  if (tid < O){
    float t1 = 0.f, t2 = 0.f;
    for (int gg = 0; gg < Ppar; ++gg){ t1 += r1[gg*O + tid]; t2 += r2[gg*O + tid]; }
    gp1[(size_t)tid*GBLK + blockIdx.x] = t1;
    gp2[(size_t)tid*GBLK + blockIdx.x] = t2;
  }
}

// ---------------- deterministic partial reduce ----------------
__global__ __launch_bounds__(256) void k_pred(const float* __restrict__ gp1, const float* __restrict__ gp2,
                                              float* __restrict__ S1, float* __restrict__ S2){
  __shared__ float r1[256], r2[256];
  int o = blockIdx.x, t = threadIdx.x;
  float a = 0.f, b = 0.f;
  #pragma unroll
  for (int i = 0; i < GBLK/256; ++i){
    a += gp1[(size_t)o*GBLK + i*256 + t];
    b += gp2[(size_t)o*GBLK + i*256 + t];
  }
  r1[t] = a; r2[t] = b;
  __syncthreads();
  for (int off = 128; off > 0; off >>= 1){
    if (t < off){ r1[t] += r1[t + off]; r2[t] += r2[t + off]; }
    __syncthreads();
  }
  if (t == 0){ S1[o] = r1[0]; S2[o] = r2[0]; }
}

// ---------------- finalize BN ----------------
__global__ void k_fin(const float* __restrict__ S1, const float* __restrict__ S2,
                      const float* __restrict__ g, const float* __restrict__ bb,
                      int O, float cnt, float* __restrict__ A, float* __restrict__ Bp){
  int o = blockIdx.x*256 + threadIdx.x;
  if (o >= O) return;
  float m = S1[o] / cnt;
  float var = S2[o] / cnt - m*m;
  float sc = g[o] / sqrtf(var + EPSF);
  A[o] = sc; Bp[o] = bb[o] - m*sc;
}

// ---------------- BN + leaky -> h slice ----------------
__global__ void k_bnle(const float* __restrict__ s, const float* __restrict__ A,
                       const float* __restrict__ Bp, int O, int choff, float* __restrict__ h){
  int gid = blockIdx.x*256 + threadIdx.x;
  int row = gid / O, o = gid % O;
  h[(size_t)row*HC + choff + o] = leakyf(fmaf(s[gid], A[o], Bp[o]));
}

// ---------------- h -> bf16 ----------------
__global__ void k_h2bf(const float* __restrict__ h, ushort* __restrict__ hbf){
  int gid = blockIdx.x*256 + threadIdx.x;
  float4 v = *(const float4*)&h[(size_t)gid*4];
  ushort4 o;
  o.x = f2bf(v.x); o.y = f2bf(v.y); o.z = f2bf(v.z); o.w = f2bf(v.w);
  *(ushort4*)&hbf[(size_t)gid*4] = o;
}

// ---------------- W5 -> bf16 ----------------
__global__ void k_w5cvt(const float* __restrict__ W5, ushort* __restrict__ w5bf){
  int gid = blockIdx.x*256 + threadIdx.x;
  float4 v = *(const float4*)&W5[(size_t)gid*4];
  ushort4 o;
  o.x = f2bf(v.x); o.y = f2bf(v.y); o.z = f2bf(v.z); o.w = f2bf(v.w);
  *(ushort4*)&w5bf[(size_t)gid*4] = o;
}

// ---------------- column sums of h -> 16 deterministic partials ----------------
__global__ void k_colsum(const float* __restrict__ hh, float* __restrict__ cp){
  __shared__ float red[4][64];
  int c = threadIdx.x & 63, g = threadIdx.x >> 6;
  int cb = blockIdx.x*64;
  int rbase = blockIdx.y*2048;
  float sacc = 0.f;
  for (int r = rbase + g; r < rbase + 2048; r += 4)
    sacc += hh[(size_t)r*HC + cb + c];
  red[g][c] = sacc;
  __syncthreads();
  if (threadIdx.x < 64){
    float t = red[0][c] + red[1][c] + red[2][c] + red[3][c];
    cp[(size_t)blockIdx.y*HC + cb + c] = t;
  }
}

__global__ void k_csred(const float* __restrict__ cp, float* __restrict__ cs){
  int c = blockIdx.x*256 + threadIdx.x;
  if (c >= HC) return;
  float s = 0.f;
  for (int g = 0; g < 16; ++g) s += cp[(size_t)g*HC + c];
  cs[c] = s;
}

// ---------------- SYRK partials ----------------
__global__ __launch_bounds__(256) void k_syrk(const float* __restrict__ hh, float* __restrict__ Gp){
  __shared__ float as[16][132], bs[16][132];
  int tid = threadIdx.x;
  int ib = blockIdx.x*128, jb = blockIdx.y*128;
  int k0 = blockIdx.z*1024;
  int cx = tid & 15, ry = tid >> 4;
  int skk = tid >> 4, scc = (tid & 15)*8;
  float acc[8][8] = {};
  for (int kk0 = k0; kk0 < k0 + 1024; kk0 += 16){
    {
      const float* ra = &hh[(size_t)(kk0 + skk)*HC + ib + scc];
      const float* rb2 = &hh[(size_t)(kk0 + skk)*HC + jb + scc];
      float4 a0 = *(const float4*)ra, a1 = *(const float4*)(ra + 4);
      float4 b0 = *(const float4*)rb2, b1 = *(const float4*)(rb2 + 4);
      *(float4*)&as[skk][scc] = a0; *(float4*)&as[skk][scc+4] = a1;
      *(float4*)&bs[skk][scc] = b0; *(float4*)&bs[skk][scc+4] = b1;
    }
    __syncthreads();
    #pragma unroll
    for (int kk = 0; kk < 16; ++kk){
      float4 a0 = *(const float4*)&as[kk][ry*8];
      float4 a1 = *(const float4*)&as[kk][ry*8+4];
      float4 b0 = *(const float4*)&bs[kk][cx*8];
      float4 b1 = *(const float4*)&bs[kk][cx*8+4];
      float av[8] = {a0.x,a0.y,a0.z,a0.w,a1.x,a1.y,a1.z,a1.w};
      float bv[8] = {b0.x,b0.y,b0.z,b0.w,b1.x,b1.y,b1.z,b1.w};
      #pragma unroll
      for (int i = 0; i < 8; ++i)
        #pragma unroll
        for (int j = 0; j < 8; ++j)
          acc[i][j] = fmaf(av[i], bv[j], acc[i][j]);
    }
    __syncthreads();
  }
  float* gz = Gp + (size_t)blockIdx.z*HC*HC;
  #pragma unroll
  for (int i = 0; i < 8; ++i){
    size_t row = (size_t)(ib + ry*8 + i);
    *(float4*)&gz[row*HC + jb + cx*8]     = make_float4(acc[i][0], acc[i][1], acc[i][2], acc[i][3]);
    *(float4*)&gz[row*HC + jb + cx*8 + 4] = make_float4(acc[i][4], acc[i][5], acc[i][6], acc[i][7]);
  }
}

// ---------------- reduce SYRK partials ----------------
__global__ void k_gred(const float* __restrict__ Gp, float* __restrict__ G){
  int e = blockIdx.x*256 + threadIdx.x;
  float s = 0.f;
  for (int z = 0; z < 32; ++z) s += Gp[(size_t)z*HC*HC + e];
  G[e] = s;
}

// ---------------- quadratic forms ----------------
__global__ __launch_bounds__(256) void k_quad(const float* __restrict__ G, const float* __restrict__ W5,
                                              const float* __restrict__ cs,
                                              float* __restrict__ S1, float* __restrict__ S2){
  __shared__ float wsh[512];
  __shared__ float red[256];
  int o = blockIdx.x, tid = threadIdx.x;
  for (int j = tid; j < 512; j += 256) wsh[j] = W5[(size_t)o*HC + j];
  __syncthreads();
  float q = 0.f;
  for (int i = tid; i < 512; i += 256){
    float wi = wsh[i];
    float rd = 0.f;
    for (int j = 0; j < 512; j += 4){
      float4 gv = *(const float4*)&G[(size_t)i*HC + j];
      rd = fmaf(gv.x, wsh[j], rd); rd = fmaf(gv.y, wsh[j+1], rd);
      rd = fmaf(gv.z, wsh[j+2], rd); rd = fmaf(gv.w, wsh[j+3], rd);
    }
    q = fmaf(wi, rd, q);
  }
  float m = 0.f;
  for (int j = tid; j < 512; j += 256) m = fmaf(wsh[j], cs[j], m);
  red[tid] = q; __syncthreads();
  for (int off = 128; off > 0; off >>= 1){ if (tid < off) red[tid] += red[tid + off]; __syncthreads(); }
  if (tid == 0) S2[o] = red[0];
  __syncthreads();
  red[tid] = m; __syncthreads();
  for (int off = 128; off > 0; off >>= 1){ if (tid < off) red[tid] += red[tid + off]; __syncthreads(); }
  if (tid == 0) S1[o] = red[0];
}

// ---------------- layer5 GEMM via MFMA bf16 (R14-validated) ----------------
__global__ __launch_bounds__(256) void k_gemm5m(const ushort* __restrict__ hbf, const ushort* __restrict__ w5bf,
                                                const float* __restrict__ A, const float* __restrict__ Bp,
                                                float* __restrict__ mpart, float* __restrict__ spart){
  __shared__ ushort lh[128][40];
  __shared__ ushort lw[128][40];
  __shared__ float redm[4][128], reds[4][128];
  int tid = threadIdx.x;
  int rb = blockIdx.x*128, ob = blockIdx.y*128;
  int wid = tid >> 6, lane = tid & 63;
  int lrow = lane & 15, lk = lane >> 4;
  f32x4 acc[2][8];
  #pragma unroll
  for (int i = 0; i < 2; ++i)
    #pragma unroll
    for (int j = 0; j < 8; ++j)
      acc[i][j] = (f32x4){0.f, 0.f, 0.f, 0.f};
  int srow = tid >> 1, shalf = tid & 1;
  for (int kt = 0; kt < 16; ++kt){
    int k0 = kt*32;
    const uint4* gh = (const uint4*)&hbf[(size_t)(rb+srow)*HC + k0 + shalf*16];
    uint4 v0 = gh[0], v1 = gh[1];
    const uint4* gw = (const uint4*)&w5bf[(size_t)(ob+srow)*HC + k0 + shalf*16];
    uint4 w0 = gw[0], w1 = gw[1];
    __syncthreads();
    *(uint4*)&lh[srow][shalf*16]     = v0;
    *(uint4*)&lh[srow][shalf*16 + 8] = v1;
    *(uint4*)&lw[srow][shalf*16]     = w0;
    *(uint4*)&lw[srow][shalf*16 + 8] = w1;
    __syncthreads();
    bf16x8 afr0 = *(const bf16x8*)&lh[wid*32 + lrow][lk*8];
    bf16x8 afr1 = *(const bf16x8*)&lh[wid*32 + 16 + lrow][lk*8];
    #pragma unroll
    for (int ct = 0; ct < 8; ++ct){
      bf16x8 bfr = *(const bf16x8*)&lw[ct*16 + lrow][lk*8];
      acc[0][ct] = __builtin_amdgcn_mfma_f32_16x16x32_bf16(afr0, bfr, acc[0][ct], 0, 0, 0);
      acc[1][ct] = __builtin_amdgcn_mfma_f32_16x16x32_bf16(afr1, bfr, acc[1][ct], 0, 0, 0);
    }
  }
  float mx[8], sm[8];
  #pragma unroll
  for (int ct = 0; ct < 8; ++ct){
    int o = ob + ct*16 + lrow;
    float Ao = A[o], Bo = Bp[o];
    float m = -FLT_MAX, s = 0.f;
    #pragma unroll
    for (int tA = 0; tA < 2; ++tA)
      #pragma unroll
      for (int q = 0; q < 4; ++q){
        float y = leakyf(fmaf(acc[tA][ct][q], Ao, Bo));
        m = fmaxf(m, y); s += y;
      }
    #pragma unroll
    for (int off = 16; off < 64; off <<= 1){
      m = fmaxf(m, __shfl_xor(m, off, 64));
      s += __shfl_xor(s, off, 64);
    }
    mx[ct] = m; sm[ct] = s;
  }
  __syncthreads();
  if (lane < 16){
    #pragma unroll
    for (int ct = 0; ct < 8; ++ct){
      redm[wid][ct*16 + lane] = mx[ct];
      reds[wid][ct*16 + lane] = sm[ct];
    }
  }
  __syncthreads();
  if (tid < 128){
    float m = fmaxf(fmaxf(redm[0][tid], redm[1][tid]), fmaxf(redm[2][tid], redm[3][tid]));
    float s = reds[0][tid] + reds[1][tid] + reds[2][tid] + reds[3][tid];
    int bbi = rb / NN, ntile = (rb % NN) >> 7;
    int o = ob + tid;
    mpart[((size_t)bbi*O5 + o)*16 + ntile] = m;
    spart[((size_t)bbi*O5 + o)*16 + ntile] = s;
  }
}

// ---------------- pool partials -> p ----------------
__global__ void k_pool(const float* __restrict__ mpart, const float* __restrict__ spart,
                       float* __restrict__ p){
  int gid = blockIdx.x*256 + threadIdx.x;
  if (gid >= BB*O5) return;
  int b = gid / O5, o = gid % O5;
  const float* mp = mpart + (size_t)(b*O5 + o)*16;
  const float* sp = spart + (size_t)(b*O5 + o)*16;
  float mx = -FLT_MAX, sm = 0.f;
  for (int t = 0; t < 16; ++t){ mx = fmaxf(mx, mp[t]); sm += sp[t]; }
  p[(size_t)b*2048 + o] = mx;
  p[(size_t)b*2048 + 1024 + o] = sm * (1.f/2048.f);
}

// ---------------- z = p @ Wl.T then BN over batch ----------------
__global__ __launch_bounds__(256) void k_final(const float* __restrict__ p, const float* __restrict__ Wl,
                                               const float* __restrict__ g6, const float* __restrict__ b6,
                                               float* __restrict__ out){
  __shared__ float red[16][257];
  int oc = blockIdx.x, tid = threadIdx.x;
  float acc[16] = {};
  for (int j = tid; j < 2048; j += 256){
    float w = Wl[(size_t)oc*2048 + j];
    #pragma unroll
    for (int b = 0; b < 16; ++b) acc[b] = fmaf(p[(size_t)b*2048 + j], w, acc[b]);
  }
  #pragma unroll
  for (int b = 0; b < 16; ++b) red[b][tid] = acc[b];
  __syncthreads();
  for (int off = 128; off > 0; off >>= 1){
    if (tid < off){
      #pragma unroll
      for (int b = 0; b < 16; ++b) red[b][tid] += red[b][tid + off];
    }
    __syncthreads();
  }
  if (tid == 0){
    float m = 0.f;
    for (int b = 0; b < 16; ++b) m += red[b][0];
    m *= (1.f/16.f);
    float var = 0.f;
    for (int b = 0; b < 16; ++b){ float d = red[b][0] - m; var = fmaf(d, d, var); }
    var *= (1.f/16.f);
    float sc = g6[oc] / sqrtf(var + EPSF);
    for (int b = 0; b < 16; ++b) out[(size_t)b*256 + oc] = (red[b][0] - m)*sc + b6[oc];
  }
}

extern "C" void kernel_launch(void* const* d_in, const int* in_sizes, int n_in,
                              void* d_out, int out_size, void* d_ws, size_t ws_size,
                              hipStream_t stream){
  const float* x  = (const float*)d_in[0];
  const float* W1 = (const float*)d_in[1];  const float* g1 = (const float*)d_in[2];  const float* b1 = (const float*)d_in[3];
  const float* W2 = (const float*)d_in[4];  const float* g2 = (const float*)d_in[5];  const float* b2 = (const float*)d_in[6];
  const float* W3 = (const float*)d_in[7];  const float* g3 = (const float*)d_in[8];  const float* b3 = (const float*)d_in[9];
  const float* W4 = (const float*)d_in[10]; const float* g4 = (const float*)d_in[11]; const float* b4 = (const float*)d_in[12];
  const float* W5 = (const float*)d_in[13]; const float* g5 = (const float*)d_in[14]; const float* b5 = (const float*)d_in[15];
  const float* Wl = (const float*)d_in[16]; const float* g6 = (const float*)d_in[17]; const float* b6 = (const float*)d_in[18];
  float* out = (float*)d_out;

  float* ws = (float*)d_ws;
  size_t off = 0;
  auto alloc = [&](size_t n){ float* pp = ws + off; off += n; return pp; };
  float* h    = alloc((size_t)BB*NN*HC);     // 64 MB
  float* u    = alloc((size_t)BB*NN*256);    // 32 MB (aliased by Gp after layer 4)
  float* v    = alloc((size_t)BB*NN*256);
  float* s    = alloc((size_t)BB*NN*256);    // 33.5 MB (aliased by hbf after layer 4)
  float* xP   = alloc((size_t)BB*NN*4);
  float* sqn  = alloc((size_t)BB*NN);
  int*   idxA = (int*)alloc((size_t)BB*NN*KNNK);
  int*   idxB = (int*)alloc((size_t)BB*NN*KNNK);
  float* wu   = alloc(256*128);
  float* wv   = alloc(256*128);
  float* S1   = alloc(1024);
  float* S2   = alloc(1024);
  float* Ab   = alloc(1024);
  float* Bb   = alloc(1024);
  float* mpart= alloc((size_t)BB*O5*16);
  float* spart= alloc((size_t)BB*O5*16);
  float* pbuf = alloc((size_t)BB*2048);
  float* G    = alloc((size_t)HC*HC);
  float* cs   = alloc(HC);
  float* cp   = alloc((size_t)16*HC);
  float* gp1  = alloc((size_t)256*GBLK);
  float* gp2  = alloc((size_t)256*GBLK);
  ushort* w5bf = (ushort*)alloc(262144);     // 1 MB (O5*HC bf16)
  float* Gp   = u;                           // 32 MB, reuses u (dead after layer 4)
  ushort* hbf = (ushort*)s;                  // 33.5 MB, reuses s (dead after layer 4)

  k_transpose<<<(BB*NN)/256, 256, 0, stream>>>(x, xP);

  struct Cfg { const float* xin; int xs, C, O, choff; const float* W; const float* g; const float* bb; };
  Cfg cfg[4] = {
    { xP,    4,   3,   64,   0, W1, g1, b1 },
    { h,     HC,  64,  64,  64, W2, g2, b2 },
    { h+64,  HC,  64, 128, 128, W3, g3, b3 },
    { h+128, HC, 128, 256, 256, W4, g4, b4 },
  };

  int* cur = idxA;
  int* prv = idxB;
  for (int i = 0; i < 4; ++i){
    const Cfg& c = cfg[i];
    k_sqn<<<(BB*NN)/256, 256, 0, stream>>>(c.xin, c.xs, c.C, sqn);
    if (i == 0)           k_knn<3,512,4,false><<<(BB*NN)/16, 256, 0, stream>>>(c.xin, c.xs, sqn, nullptr, cur);
    else if (c.C == 64)   k_knn<64,256,8,true><<<(BB*NN)/32, 256, 0, stream>>>(c.xin, c.xs, sqn, prv, cur);
    else                  k_knn<128,256,8,true><<<(BB*NN)/32, 256, 0, stream>>>(c.xin, c.xs, sqn, prv, cur);
    int OC = c.O * c.C;
    k_wprep<<<(OC + 255)/256, 256, 0, stream>>>(c.W, c.O, c.C, wu, wv);
    k_uv<<<dim3((BB*NN)/64, c.O/64), 256, 0, stream>>>(c.xin, c.xs, c.C, wu, wv, c.O, u, v);
    k_gather<<<GBLK, 256, 0, stream>>>(u, v, cur, c.O, s, gp1, gp2);
    k_pred<<<c.O, 256, 0, stream>>>(gp1, gp2, S1, S2);
    k_fin<<<4, 256, 0, stream>>>(S1, S2, c.g, c.bb, c.O, (float)((size_t)BB*NN*KNNK), Ab, Bb);
    k_bnle<<<((size_t)BB*NN*c.O)/256, 256, 0, stream>>>(s, Ab, Bb, c.O, c.choff, h);
    int* t = cur; cur = prv; prv = t;
  }

  // convert h and W5 to bf16 for the MFMA layer-5 GEMM
  k_h2bf<<<((size_t)BB*NN*HC)/(256*4), 256, 0, stream>>>(h, hbf);
  k_w5cvt<<<((size_t)O5*HC)/(256*4), 256, 0, stream>>>(W5, w5bf);

  // layer 5 stats via covariance: S2 = w^T (h^T h) w, S1 = w . colsum(h)
  k_colsum<<<dim3(8, 16), 256, 0, stream>>>(h, cp);
  k_csred<<<2, 256, 0, stream>>>(cp, cs);
  k_syrk<<<dim3(4, 4, 32), 256, 0, stream>>>(h, Gp);
  k_gred<<<(HC*HC)/256, 256, 0, stream>>>(Gp, G);
  k_quad<<<O5, 256, 0, stream>>>(G, W5, cs, S1, S2);
  k_fin<<<4, 256, 0, stream>>>(S1, S2, g5, b5, O5, (float)((size_t)BB*NN), Ab, Bb);
  k_gemm5m<<<dim3((BB*NN)/128, O5/128), 256, 0, stream>>>(hbf, w5bf, Ab, Bb, mpart, spart);
  k_pool<<<(BB*O5)/256, 256, 0, stream>>>(mpart, spart, pbuf);

  k_final<<<256, 256, 0, stream>>>(pbuf, Wl, g6, b6, out);
}

// Round 18
// 2134.269 us; speedup vs baseline: 1.1904x; 1.1904x over previous
//
#include <hip/hip_runtime.h>
#include <float.h>
#include <math.h>

#define BB 16
#define NN 2048
#define KNNK 20
#define HC 512
#define O5 1024
#define EPSF 1e-5f
#define GBLK 2048   // number of k_gather blocks (= BB*NN/16)

typedef short bf16x8 __attribute__((ext_vector_type(8)));
typedef float f32x4 __attribute__((ext_vector_type(4)));

__device__ __forceinline__ float leakyf(float y){ return y > 0.f ? y : 0.2f*y; }

__device__ __forceinline__ ushort f2bf(float f){
  unsigned u = __float_as_uint(f);
  unsigned r = (u + 0x7fffu + ((u >> 16) & 1u)) >> 16;
  return (ushort)r;
}

// one bitonic compare-exchange step over 64 lanes; order: value desc, index asc
// (hardware-validated R8/R10/R11/R12)
__device__ __forceinline__ void bsort_step(float& v, int& id, int lane, int k, int j){
  float pv = __shfl_xor(v, j, 64);
  int pid = __shfl_xor(id, j, 64);
  bool up = ((lane & k) == 0);
  bool iLow = ((lane & j) == 0);
  bool pBefore = (pv > v) || (pv == v && pid < id);
  if ((up == iLow) ? pBefore : !pBefore){ v = pv; id = pid; }
}

// ---------------- transpose x (B,3,N) -> xP (B,N,4) padded ----------------
__global__ void k_transpose(const float* __restrict__ x, float* __restrict__ xP){
  int gid = blockIdx.x*256 + threadIdx.x;
  if (gid >= BB*NN) return;
  int b = gid / NN, n = gid % NN;
  const float* xb = x + (size_t)b*3*NN;
  *(float4*)&xP[(size_t)gid*4] = make_float4(xb[n], xb[NN + n], xb[2*NN + n], 0.f);
}

// ---------------- squared norms ----------------
__global__ void k_sqn(const float* __restrict__ xin, int xs, int C, float* __restrict__ sqn){
  int gid = blockIdx.x*256 + threadIdx.x;
  if (gid >= BB*NN) return;
  const float* r = xin + (size_t)gid*xs;
  float s = 0.f;
  for (int c = 0; c < C; ++c){ float v = r[c]; s = fmaf(v, v, s); }
  sqn[gid] = s;
}

// ---------------- KNN: 256 thr = 4 waves x 4 rows (R14 best-validated config) ----------------
// Cold (layer 1, C=3, MC=256): extraction + inserts (R6-proven).
// Warm (layers 2-4, MC=256): warm-start top-20 from prev layer (R11),
//   coalesced LDS staging of m-points (R13), uniform-scalar query reads (R12).
// Ascending-channel fmaf chains everywhere -> bit-exact -> identical top-20.
template<int C, int MC, int RW, bool WARM>
__global__ __launch_bounds__(256) void k_knn(const float* __restrict__ xin, int xs,
                                             const float* __restrict__ sqn,
                                             const int* __restrict__ idx_prev,
                                             int* __restrict__ idx_out){
  const int TN = 4*RW;
  const int NPL = MC/64;
  const int LNPL = (NPL == 8) ? 3 : 2;
  __shared__ float xnT[WARM ? 1 : 8][20];
  __shared__ float xmT[(C == 3 ? 1 : 16)][MC + 4];
  __shared__ float cval[TN][24];
  __shared__ int   cidx[TN][24];
  __shared__ float sqnn[TN];
  int tid = threadIdx.x;
  int b = (blockIdx.x*TN) / NN, n0 = (blockIdx.x*TN) % NN;
  const float* xb = xin + (size_t)b*NN*xs;

  if constexpr (!WARM){
    for (int e = tid; e < TN*C; e += 256){
      int r = e / C, c = e % C;
      xnT[c][r] = xb[(size_t)(n0+r)*xs + c];
    }
  }
  if (tid < TN) sqnn[tid] = sqn[b*NN + n0 + tid];
  __syncthreads();

  int wid = tid >> 6, lane = tid & 63, r0 = wid*RW;
  float tv[RW]; int ti[RW];

  int urow[RW];
  #pragma unroll
  for (int i = 0; i < RW; ++i) urow[i] = __builtin_amdgcn_readfirstlane(n0 + r0 + i);

  if constexpr (WARM){
    #pragma unroll
    for (int i = 0; i < RW; ++i){
      int r = r0 + i;
      int m = (lane < KNNK) ? idx_prev[(size_t)(b*NN + n0 + r)*KNNK + lane] : 0;
      const float* xq = xb + (size_t)urow[i]*xs;
      const float* xm = xb + (size_t)m*xs;
      float dot = 0.f;
      #pragma unroll 8
      for (int c = 0; c < C; c += 4){
        float4 qv = *(const float4*)(xq + c);
        float4 mv = *(const float4*)(xm + c);
        dot = fmaf(qv.x, mv.x, dot);
        dot = fmaf(qv.y, mv.y, dot);
        dot = fmaf(qv.z, mv.z, dot);
        dot = fmaf(qv.w, mv.w, dot);
      }
      float dval = (lane < KNNK) ? ((2.f*dot - sqnn[r]) - sqn[b*NN + m]) : -FLT_MAX;
      int did = (lane < KNNK) ? m : 0x7fffffff;
      #pragma unroll
      for (int k = 2; k <= 64; k <<= 1)
        #pragma unroll
        for (int jj = k >> 1; jj > 0; jj >>= 1)
          bsort_step(dval, did, lane, k, jj);
      if (lane < KNNK){ cval[r][lane] = dval; cidx[r][lane] = did; }
      tv[i] = __shfl(dval, KNNK-1); ti[i] = __shfl(did, KNNK-1);
    }
    __syncthreads();
  }

  for (int base = 0; base < NN; base += MC){
    float pd[RW][NPL];
    if constexpr (C == 3){
      int m0g = base + lane*NPL;
      const float* xm = xb + (size_t)m0g*4;
      float4 q[NPL];
      #pragma unroll
      for (int j = 0; j < NPL; ++j) q[j] = *(const float4*)&xm[j*4];
      float smr[NPL];
      #pragma unroll
      for (int j = 0; j < NPL; j += 4){
        float4 s4 = *(const float4*)&sqn[b*NN + m0g + j];
        smr[j] = s4.x; smr[j+1] = s4.y; smr[j+2] = s4.z; smr[j+3] = s4.w;
      }
      #pragma unroll
      for (int i = 0; i < RW; ++i){
        float a0 = xnT[0][r0+i], a1 = xnT[1][r0+i], a2 = xnT[2][r0+i], sq = sqnn[r0+i];
        #pragma unroll
        for (int j = 0; j < NPL; ++j){
          float d = a0*q[j].x; d = fmaf(a1, q[j].y, d); d = fmaf(a2, q[j].z, d);
          pd[i][j] = (2.f*d - sq) - smr[j];
        }
      }
    } else {
      // COALESCED LDS staging (R13/R14-validated): 4 threads/point, 64B contiguous segs
      float acc[RW][4];
      #pragma unroll
      for (int i = 0; i < RW; ++i)
        #pragma unroll
        for (int p = 0; p < 4; ++p) acc[i][p] = 0.f;
      int pm = tid >> 2, fq = tid & 3;
      for (int c0 = 0; c0 < C; c0 += 16){
        #pragma unroll
        for (int p = 0; p < MC/64; ++p){
          int pt = p*64 + pm;
          float4 vv = *(const float4*)(xb + (size_t)(base + pt)*xs + c0 + fq*4);
          xmT[fq*4+0][pt] = vv.x; xmT[fq*4+1][pt] = vv.y;
          xmT[fq*4+2][pt] = vv.z; xmT[fq*4+3][pt] = vv.w;
        }
        __syncthreads();
        #pragma unroll
        for (int cc4 = 0; cc4 < 16; cc4 += 4){
          float aq[RW][4];
          #pragma unroll
          for (int i = 0; i < RW; ++i)
            *(float4*)&aq[i][0] = *(const float4*)(xb + (size_t)urow[i]*xs + c0 + cc4);
          #pragma unroll
          for (int dc = 0; dc < 4; ++dc){
            float4 m4 = *(const float4*)&xmT[cc4+dc][lane*4];
            float mv[4] = {m4.x, m4.y, m4.z, m4.w};
            #pragma unroll
            for (int i = 0; i < RW; ++i)
              #pragma unroll
              for (int p = 0; p < 4; ++p)
                acc[i][p] = fmaf(aq[i][dc], mv[p], acc[i][p]);
          }
        }
        __syncthreads();
      }
      float4 sm4 = *(const float4*)&sqn[b*NN + base + lane*4];
      float smr[4] = {sm4.x, sm4.y, sm4.z, sm4.w};
      #pragma unroll
      for (int i = 0; i < RW; ++i){
        float sq = sqnn[r0+i];
        #pragma unroll
        for (int j = 0; j < 4; ++j)
          pd[i][j] = (2.f*acc[i][j] - sq) - smr[j];
      }
    }

    bool handled = false;
    if constexpr (!WARM){
      if (base == 0){
        handled = true;
        // interleaved sorted top-20 extraction (RW rows together), NPL-generic
        float lv[RW]; int li[RW];
        #pragma unroll
        for (int i = 0; i < RW; ++i){
          float v0 = pd[i][0]; int j0 = 0;
          #pragma unroll
          for (int j = 1; j < NPL; ++j) if (pd[i][j] > v0){ v0 = pd[i][j]; j0 = j; }
          lv[i] = v0; li[i] = lane*NPL + j0;
        }
        float bv[RW]; int bi[RW];
        for (int it = 0; it < KNNK; ++it){
          #pragma unroll
          for (int i = 0; i < RW; ++i){ bv[i] = lv[i]; bi[i] = li[i]; }
          #pragma unroll
          for (int off = 1; off < 64; off <<= 1){
            #pragma unroll
            for (int i = 0; i < RW; ++i){
              float ov = __shfl_xor(bv[i], off, 64);
              int oi = __shfl_xor(bi[i], off, 64);
              if (ov > bv[i] || (ov == bv[i] && oi < bi[i])){ bv[i] = ov; bi[i] = oi; }
            }
          }
          #pragma unroll
          for (int i = 0; i < RW; ++i){
            if (lane == it){ cval[r0+i][it] = bv[i]; cidx[r0+i][it] = bi[i]; }
            int wl = bi[i] >> LNPL, wj = bi[i] & (NPL - 1);
            if (lane == wl){
              #pragma unroll
              for (int j = 0; j < NPL; ++j) if (j == wj) pd[i][j] = -FLT_MAX;
              float v0 = pd[i][0]; int j0 = 0;
              #pragma unroll
              for (int j = 1; j < NPL; ++j) if (pd[i][j] > v0){ v0 = pd[i][j]; j0 = j; }
              lv[i] = v0; li[i] = lane*NPL + j0;
            }
          }
        }
        #pragma unroll
        for (int i = 0; i < RW; ++i){ tv[i] = bv[i]; ti[i] = bi[i]; }
      }
    }
    if (!handled){
      #pragma unroll
      for (int i = 0; i < RW; ++i){
        int r = r0 + i;
        bool pred = false;
        #pragma unroll
        for (int j = 0; j < NPL; ++j){
          int ci = base + lane*NPL + j;
          pred = pred || (pd[i][j] > tv[i]) || (pd[i][j] == tv[i] && ci < ti[i]);
        }
        unsigned long long mask = __ballot(pred);
        while (mask){
          int l = __builtin_ctzll(mask); mask &= (mask - 1);
          float cvv[NPL];
          #pragma unroll
          for (int j = 0; j < NPL; ++j) cvv[j] = __shfl(pd[i][j], l);
          #pragma unroll
          for (int j = 0; j < NPL; ++j){
            float cv = cvv[j];
            int ci = base + l*NPL + j;
            if (cv > tv[i] || (cv == tv[i] && ci < ti[i])){
              bool skip = false;
              if constexpr (WARM){
                skip = __ballot((lane < KNNK) && (cidx[r][lane] == ci)) != 0ull;
              }
              if (!skip){
                float ev = -FLT_MAX; int ei = 0x7fffffff;
                if (lane < KNNK){ ev = cval[r][lane]; ei = cidx[r][lane]; }
                bool ahead = (lane < KNNK) && (ev > cv || (ev == cv && ei < ci));
                int pos = __popcll(__ballot(ahead));
                float pev = __shfl_up(ev, 1);
                int   pei = __shfl_up(ei, 1);
                float nv; int ni;
                if (lane < pos){ nv = ev; ni = ei; }
                else if (lane == pos){ nv = cv; ni = ci; }
                else { nv = pev; ni = pei; }
                if (lane < KNNK){ cval[r][lane] = nv; cidx[r][lane] = ni; }
                tv[i] = __shfl(nv, 19); ti[i] = __shfl(ni, 19);
              }
            }
          }
        }
      }
    }
  }

  if (lane < KNNK){
    #pragma unroll
    for (int i = 0; i < RW; ++i){
      int r = r0 + i;
      idx_out[(size_t)(b*NN + n0 + r)*KNNK + lane] = cidx[r][lane];
    }
  }
}

// ---------------- weight prep ----------------
__global__ void k_wprep(const float* __restrict__ W, int O, int C,
                        float* __restrict__ wu, float* __restrict__ wv){
  int i = blockIdx.x*256 + threadIdx.x;
  if (i >= O*C) return;
  int o = i / C, c = i % C;
  float a = W[(size_t)o*2*C + c], b = W[(size_t)o*2*C + C + c];
  wu[i] = a; wv[i] = b - a;
}

// ---------------- u,v GEMM ----------------
__global__ __launch_bounds__(256) void k_uv(const float* __restrict__ xin, int xs, int C,
                                            const float* __restrict__ wu, const float* __restrict__ wv,
                                            int O, float* __restrict__ u, float* __restrict__ v){
  __shared__ float xsh[16][68];
  __shared__ float wush[16][68], wvsh[16][68];
  int tid = threadIdx.x;
  int rb = blockIdx.x*64, ob = blockIdx.y*64;
  int otx = tid % 16, rty = tid / 16;
  float au[4][4] = {}, av[4][4] = {};
  for (int c0 = 0; c0 < C; c0 += 16){
    #pragma unroll
    for (int i = 0; i < 4; ++i){
      int c = otx, r = rty*4 + i;
      xsh[c][r]  = (c0 + c < C) ? xin[(size_t)(rb+r)*xs + c0 + c] : 0.f;
      wush[c][r] = (c0 + c < C) ? wu[(size_t)(ob+r)*C + c0 + c] : 0.f;
      wvsh[c][r] = (c0 + c < C) ? wv[(size_t)(ob+r)*C + c0 + c] : 0.f;
    }
    __syncthreads();
    #pragma unroll
    for (int c = 0; c < 16; ++c){
      float4 xr = *(const float4*)&xsh[c][rty*4];
      float4 wa = *(const float4*)&wush[c][otx*4];
      float4 wb = *(const float4*)&wvsh[c][otx*4];
      float xv[4] = {xr.x, xr.y, xr.z, xr.w};
      float wav[4] = {wa.x, wa.y, wa.z, wa.w};
      float wbv[4] = {wb.x, wb.y, wb.z, wb.w};
      #pragma unroll
      for (int i = 0; i < 4; ++i)
        #pragma unroll
        for (int j = 0; j < 4; ++j){
          au[i][j] = fmaf(xv[i], wav[j], au[i][j]);
          av[i][j] = fmaf(xv[i], wbv[j], av[i][j]);
        }
    }
    __syncthreads();
  }
  #pragma unroll
  for (int i = 0; i < 4; ++i){
    size_t r = (size_t)(rb + rty*4 + i);
    *(float4*)&u[r*O + ob + otx*4] = make_float4(au[i][0], au[i][1], au[i][2], au[i][3]);
    *(float4*)&v[r*O + ob + otx*4] = make_float4(av[i][0], av[i][1], av[i][2], av[i][3]);
  }
}

// ---------------- gather + max/sum/sumsq -> deterministic partials ----------------
__global__ __launch_bounds__(256) void k_gather(const float* __restrict__ u, const float* __restrict__ v,
                                                const int* __restrict__ idx, int O,
                                                float* __restrict__ s,
                                                float* __restrict__ gp1, float* __restrict__ gp2){
  __shared__ float r1[256], r2[256];
  int tid = threadIdx.x;
  int Ppar = 256 / O;
  int o = tid % O, g = tid / O;
  int p0 = blockIdx.x*16;
  float cs = 0.f, cs2 = 0.f;
  int IT = 16 / Ppar;
  for (int it = 0; it < IT; ++it){
    int pi = p0 + it*Ppar + g;
    int b = pi / NN;
    const int* il = idx + (size_t)pi*KNNK;
    float vv = v[(size_t)pi*O + o];
    float mx = -FLT_MAX, su = 0.f, su2 = 0.f;
    #pragma unroll
    for (int k = 0; k < KNNK; ++k){
      int m = il[k];
      float um = u[((size_t)b*NN + m)*O + o];
      mx = fmaxf(mx, um); su += um; su2 = fmaf(um, um, su2);
    }
    s[(size_t)pi*O + o] = mx + vv;
    cs += su + (float)KNNK*vv;
    cs2 += su2 + 2.f*vv*su + (float)KNNK*vv*vv;
  }
  r1[tid] = cs; r2[tid] = cs2;
  __syncthreads();
  if (tid < O){
    float t1 = 0.f, t2 = 0.f;
    for (int gg = 0; gg < Ppar; ++gg){ t1 += r1[gg*O + tid]; t2 += r2[gg*O + tid]; }
    gp1[(size_t)tid*GBLK + blockIdx.x] = t1;
    gp2[(size_t)tid*GBLK + blockIdx.x] = t2;
  }
}

// ---------------- deterministic partial reduce ----------------
__global__ __launch_bounds__(256) void k_pred(const float* __restrict__ gp1, const float* __restrict__ gp2,
                                              float* __restrict__ S1, float* __restrict__ S2){
  __shared__ float r1[256], r2[256];
  int o = blockIdx.x, t = threadIdx.x;
  float a = 0.f, b = 0.f;
  #pragma unroll
  for (int i = 0; i < GBLK/256; ++i){
    a += gp1[(size_t)o*GBLK + i*256 + t];
    b += gp2[(size_t)o*GBLK + i*256 + t];
  }
  r1[t] = a; r2[t] = b;
  __syncthreads();
  for (int off = 128; off > 0; off >>= 1){
    if (t < off){ r1[t] += r1[t + off]; r2[t] += r2[t + off]; }
    __syncthreads();
  }
  if (t == 0){ S1[o] = r1[0]; S2[o] = r2[0]; }
}

// ---------------- finalize BN ----------------
__global__ void k_fin(const float* __restrict__ S1, const float* __restrict__ S2,
                      const float* __restrict__ g, const float* __restrict__ bb,
                      int O, float cnt, float* __restrict__ A, float* __restrict__ Bp){
  int o = blockIdx.x*256 + threadIdx.x;
  if (o >= O) return;
  float m = S1[o] / cnt;
  float var = S2[o] / cnt - m*m;
  float sc = g[o] / sqrtf(var + EPSF);
  A[o] = sc; Bp[o] = bb[o] - m*sc;
}

// ---------------- BN + leaky -> h slice ----------------
__global__ void k_bnle(const float* __restrict__ s, const float* __restrict__ A,
                       const float* __restrict__ Bp, int O, int choff, float* __restrict__ h){
  int gid = blockIdx.x*256 + threadIdx.x;
  int row = gid / O, o = gid % O;
  h[(size_t)row*HC + choff + o] = leakyf(fmaf(s[gid], A[o], Bp[o]));
}

// ---------------- h -> bf16 ----------------
__global__ void k_h2bf(const float* __restrict__ h, ushort* __restrict__ hbf){
  int gid = blockIdx.x*256 + threadIdx.x;
  float4 v = *(const float4*)&h[(size_t)gid*4];
  ushort4 o;
  o.x = f2bf(v.x); o.y = f2bf(v.y); o.z = f2bf(v.z); o.w = f2bf(v.w);
  *(ushort4*)&hbf[(size_t)gid*4] = o;
}

// ---------------- W5 -> bf16 ----------------
__global__ void k_w5cvt(const float* __restrict__ W5, ushort* __restrict__ w5bf){
  int gid = blockIdx.x*256 + threadIdx.x;
  float4 v = *(const float4*)&W5[(size_t)gid*4];
  ushort4 o;
  o.x = f2bf(v.x); o.y = f2bf(v.y); o.z = f2bf(v.z); o.w = f2bf(v.w);
  *(ushort4*)&w5bf[(size_t)gid*4] = o;
}

// ---------------- column sums of h -> 16 deterministic partials ----------------
__global__ void k_colsum(const float* __restrict__ hh, float* __restrict__ cp){
  __shared__ float red[4][64];
  int c = threadIdx.x & 63, g = threadIdx.x >> 6;
  int cb = blockIdx.x*64;
  int rbase = blockIdx.y*2048;
  float sacc = 0.f;
  for (int r = rbase + g; r < rbase + 2048; r += 4)
    sacc += hh[(size_t)r*HC + cb + c];
  red[g][c] = sacc;
  __syncthreads();
  if (threadIdx.x < 64){
    float t = red[0][c] + red[1][c] + red[2][c] + red[3][c];
    cp[(size_t)blockIdx.y*HC + cb + c] = t;
  }
}

__global__ void k_csred(const float* __restrict__ cp, float* __restrict__ cs){
  int c = blockIdx.x*256 + threadIdx.x;
  if (c >= HC) return;
  float s = 0.f;
  for (int g = 0; g < 16; ++g) s += cp[(size_t)g*HC + c];
  cs[c] = s;
}

// ---------------- SYRK partials ----------------
__global__ __launch_bounds__(256) void k_syrk(const float* __restrict__ hh, float* __restrict__ Gp){
  __shared__ float as[16][132], bs[16][132];
  int tid = threadIdx.x;
  int ib = blockIdx.x*128, jb = blockIdx.y*128;
  int k0 = blockIdx.z*1024;
  int cx = tid & 15, ry = tid >> 4;
  int skk = tid >> 4, scc = (tid & 15)*8;
  float acc[8][8] = {};
  for (int kk0 = k0; kk0 < k0 + 1024; kk0 += 16){
    {
      const float* ra = &hh[(size_t)(kk0 + skk)*HC + ib + scc];
      const float* rb2 = &hh[(size_t)(kk0 + skk)*HC + jb + scc];
      float4 a0 = *(const float4*)ra, a1 = *(const float4*)(ra + 4);
      float4 b0 = *(const float4*)rb2, b1 = *(const float4*)(rb2 + 4);
      *(float4*)&as[skk][scc] = a0; *(float4*)&as[skk][scc+4] = a1;
      *(float4*)&bs[skk][scc] = b0; *(float4*)&bs[skk][scc+4] = b1;
    }
    __syncthreads();
    #pragma unroll
    for (int kk = 0; kk < 16; ++kk){
      float4 a0 = *(const float4*)&as[kk][ry*8];
      float4 a1 = *(const float4*)&as[kk][ry*8+4];
      float4 b0 = *(const float4*)&bs[kk][cx*8];
      float4 b1 = *(const float4*)&bs[kk][cx*8+4];
      float av[8] = {a0.x,a0.y,a0.z,a0.w,a1.x,a1.y,a1.z,a1.w};
      float bv[8] = {b0.x,b0.y,b0.z,b0.w,b1.x,b1.y,b1.z,b1.w};
      #pragma unroll
      for (int i = 0; i < 8; ++i)
        #pragma unroll
        for (int j = 0; j < 8; ++j)
          acc[i][j] = fmaf(av[i], bv[j], acc[i][j]);
    }
    __syncthreads();
  }
  float* gz = Gp + (size_t)blockIdx.z*HC*HC;
  #pragma unroll
  for (int i = 0; i < 8; ++i){
    size_t row = (size_t)(ib + ry*8 + i);
    *(float4*)&gz[row*HC + jb + cx*8]     = make_float4(acc[i][0], acc[i][1], acc[i][2], acc[i][3]);
    *(float4*)&gz[row*HC + jb + cx*8 + 4] = make_float4(acc[i][4], acc[i][5], acc[i][6], acc[i][7]);
  }
}

// ---------------- reduce SYRK partials ----------------
__global__ void k_gred(const float* __restrict__ Gp, float* __restrict__ G){
  int e = blockIdx.x*256 + threadIdx.x;
  float s = 0.f;
  for (int z = 0; z < 32; ++z) s += Gp[(size_t)z*HC*HC + e];
  G[e] = s;
}

// ---------------- quadratic forms ----------------
__global__ __launch_bounds__(256) void k_quad(const float* __restrict__ G, const float* __restrict__ W5,
                                              const float* __restrict__ cs,
                                              float* __restrict__ S1, float* __restrict__ S2){
  __shared__ float wsh[512];
  __shared__ float red[256];
  int o = blockIdx.x, tid = threadIdx.x;
  for (int j = tid; j < 512; j += 256) wsh[j] = W5[(size_t)o*HC + j];
  __syncthreads();
  float q = 0.f;
  for (int i = tid; i < 512; i += 256){
    float wi = wsh[i];
    float rd = 0.f;
    for (int j = 0; j < 512; j += 4){
      float4 gv = *(const float4*)&G[(size_t)i*HC + j];
      rd = fmaf(gv.x, wsh[j], rd); rd = fmaf(gv.y, wsh[j+1], rd);
      rd = fmaf(gv.z, wsh[j+2], rd); rd = fmaf(gv.w, wsh[j+3], rd);
    }
    q = fmaf(wi, rd, q);
  }
  float m = 0.f;
  for (int j = tid; j < 512; j += 256) m = fmaf(wsh[j], cs[j], m);
  red[tid] = q; __syncthreads();
  for (int off = 128; off > 0; off >>= 1){ if (tid < off) red[tid] += red[tid + off]; __syncthreads(); }
  if (tid == 0) S2[o] = red[0];
  __syncthreads();
  red[tid] = m; __syncthreads();
  for (int off = 128; off > 0; off >>= 1){ if (tid < off) red[tid] += red[tid + off]; __syncthreads(); }
  if (tid == 0) S1[o] = red[0];
}

// ---------------- layer5 GEMM via MFMA bf16 (R14-validated) ----------------
__global__ __launch_bounds__(256) void k_gemm5m(const ushort* __restrict__ hbf, const ushort* __restrict__ w5bf,
                                                const float* __restrict__ A, const float* __restrict__ Bp,
                                                float* __restrict__ mpart, float* __restrict__ spart){
  __shared__ ushort lh[128][40];
  __shared__ ushort lw[128][40];
  __shared__ float redm[4][128], reds[4][128];
  int tid = threadIdx.x;
  int rb = blockIdx.x*128, ob = blockIdx.y*128;
  int wid = tid >> 6, lane = tid & 63;
  int lrow = lane & 15, lk = lane >> 4;
  f32x4 acc[2][8];
  #pragma unroll
  for (int i = 0; i < 2; ++i)
    #pragma unroll
    for (int j = 0; j < 8; ++j)
      acc[i][j] = (f32x4){0.f, 0.f, 0.f, 0.f};
  int srow = tid >> 1, shalf = tid & 1;
  for (int kt = 0; kt < 16; ++kt){
    int k0 = kt*32;
    const uint4* gh = (const uint4*)&hbf[(size_t)(rb+srow)*HC + k0 + shalf*16];
    uint4 v0 = gh[0], v1 = gh[1];
    const uint4* gw = (const uint4*)&w5bf[(size_t)(ob+srow)*HC + k0 + shalf*16];
    uint4 w0 = gw[0], w1 = gw[1];
    __syncthreads();
    *(uint4*)&lh[srow][shalf*16]     = v0;
    *(uint4*)&lh[srow][shalf*16 + 8] = v1;
    *(uint4*)&lw[srow][shalf*16]     = w0;
    *(uint4*)&lw[srow][shalf*16 + 8] = w1;
    __syncthreads();
    bf16x8 afr0 = *(const bf16x8*)&lh[wid*32 + lrow][lk*8];
    bf16x8 afr1 = *(const bf16x8*)&lh[wid*32 + 16 + lrow][lk*8];
    #pragma unroll
    for (int ct = 0; ct < 8; ++ct){
      bf16x8 bfr = *(const bf16x8*)&lw[ct*16 + lrow][lk*8];
      acc[0][ct] = __builtin_amdgcn_mfma_f32_16x16x32_bf16(afr0, bfr, acc[0][ct], 0, 0, 0);
      acc[1][ct] = __builtin_amdgcn_mfma_f32_16x16x32_bf16(afr1, bfr, acc[1][ct], 0, 0, 0);
    }
  }
  float mx[8], sm[8];
  #pragma unroll
  for (int ct = 0; ct < 8; ++ct){
    int o = ob + ct*16 + lrow;
    float Ao = A[o], Bo = Bp[o];
    float m = -FLT_MAX, s = 0.f;
    #pragma unroll
    for (int tA = 0; tA < 2; ++tA)
      #pragma unroll
      for (int q = 0; q < 4; ++q){
        float y = leakyf(fmaf(acc[tA][ct][q], Ao, Bo));
        m = fmaxf(m, y); s += y;
      }
    #pragma unroll
    for (int off = 16; off < 64; off <<= 1){
      m = fmaxf(m, __shfl_xor(m, off, 64));
      s += __shfl_xor(s, off, 64);
    }
    mx[ct] = m; sm[ct] = s;
  }
  __syncthreads();
  if (lane < 16){
    #pragma unroll
    for (int ct = 0; ct < 8; ++ct){
      redm[wid][ct*16 + lane] = mx[ct];
      reds[wid][ct*16 + lane] = sm[ct];
    }
  }
  __syncthreads();
  if (tid < 128){
    float m = fmaxf(fmaxf(redm[0][tid], redm[1][tid]), fmaxf(redm[2][tid], redm[3][tid]));
    float s = reds[0][tid] + reds[1][tid] + reds[2][tid] + reds[3][tid];
    int bbi = rb / NN, ntile = (rb % NN) >> 7;
    int o = ob + tid;
    mpart[((size_t)bbi*O5 + o)*16 + ntile] = m;
    spart[((size_t)bbi*O5 + o)*16 + ntile] = s;
  }
}

// ---------------- pool partials -> p ----------------
__global__ void k_pool(const float* __restrict__ mpart, const float* __restrict__ spart,
                       float* __restrict__ p){
  int gid = blockIdx.x*256 + threadIdx.x;
  if (gid >= BB*O5) return;
  int b = gid / O5, o = gid % O5;
  const float* mp = mpart + (size_t)(b*O5 + o)*16;
  const float* sp = spart + (size_t)(b*O5 + o)*16;
  float mx = -FLT_MAX, sm = 0.f;
  for (int t = 0; t < 16; ++t){ mx = fmaxf(mx, mp[t]); sm += sp[t]; }
  p[(size_t)b*2048 + o] = mx;
  p[(size_t)b*2048 + 1024 + o] = sm * (1.f/2048.f);
}

// ---------------- z = p @ Wl.T then BN over batch ----------------
__global__ __launch_bounds__(256) void k_final(const float* __restrict__ p, const float* __restrict__ Wl,
                                               const float* __restrict__ g6, const float* __restrict__ b6,
                                               float* __restrict__ out){
  __shared__ float red[16][257];
  int oc = blockIdx.x, tid = threadIdx.x;
  float acc[16] = {};
  for (int j = tid; j < 2048; j += 256){
    float w = Wl[(size_t)oc*2048 + j];
    #pragma unroll
    for (int b = 0; b < 16; ++b) acc[b] = fmaf(p[(size_t)b*2048 + j], w, acc[b]);
  }
  #pragma unroll
  for (int b = 0; b < 16; ++b) red[b][tid] = acc[b];
  __syncthreads();
  for (int off = 128; off > 0; off >>= 1){
    if (tid < off){
      #pragma unroll
      for (int b = 0; b < 16; ++b) red[b][tid] += red[b][tid + off];
    }
    __syncthreads();
  }
  if (tid == 0){
    float m = 0.f;
    for (int b = 0; b < 16; ++b) m += red[b][0];
    m *= (1.f/16.f);
    float var = 0.f;
    for (int b = 0; b < 16; ++b){ float d = red[b][0] - m; var = fmaf(d, d, var); }
    var *= (1.f/16.f);
    float sc = g6[oc] / sqrtf(var + EPSF);
    for (int b = 0; b < 16; ++b) out[(size_t)b*256 + oc] = (red[b][0] - m)*sc + b6[oc];
  }
}

extern "C" void kernel_launch(void* const* d_in, const int* in_sizes, int n_in,
                              void* d_out, int out_size, void* d_ws, size_t ws_size,
                              hipStream_t stream){
  const float* x  = (const float*)d_in[0];
  const float* W1 = (const float*)d_in[1];  const float* g1 = (const float*)d_in[2];  const float* b1 = (const float*)d_in[3];
  const float* W2 = (const float*)d_in[4];  const float* g2 = (const float*)d_in[5];  const float* b2 = (const float*)d_in[6];
  const float* W3 = (const float*)d_in[7];  const float* g3 = (const float*)d_in[8];  const float* b3 = (const float*)d_in[9];
  const float* W4 = (const float*)d_in[10]; const float* g4 = (const float*)d_in[11]; const float* b4 = (const float*)d_in[12];
  const float* W5 = (const float*)d_in[13]; const float* g5 = (const float*)d_in[14]; const float* b5 = (const float*)d_in[15];
  const float* Wl = (const float*)d_in[16]; const float* g6 = (const float*)d_in[17]; const float* b6 = (const float*)d_in[18];
  float* out = (float*)d_out;

  float* ws = (float*)d_ws;
  size_t off = 0;
  auto alloc = [&](size_t n){ float* pp = ws + off; off += n; return pp; };
  float* h    = alloc((size_t)BB*NN*HC);     // 64 MB
  float* u    = alloc((size_t)BB*NN*256);    // 32 MB (aliased by Gp after layer 4)
  float* v    = alloc((size_t)BB*NN*256);
  float* s    = alloc((size_t)BB*NN*256);    // 33.5 MB (aliased by hbf after layer 4)
  float* xP   = alloc((size_t)BB*NN*4);
  float* sqn  = alloc((size_t)BB*NN);
  int*   idxA = (int*)alloc((size_t)BB*NN*KNNK);
  int*   idxB = (int*)alloc((size_t)BB*NN*KNNK);
  float* wu   = alloc(256*128);
  float* wv   = alloc(256*128);
  float* S1   = alloc(1024);
  float* S2   = alloc(1024);
  float* Ab   = alloc(1024);
  float* Bb   = alloc(1024);
  float* mpart= alloc((size_t)BB*O5*16);
  float* spart= alloc((size_t)BB*O5*16);
  float* pbuf = alloc((size_t)BB*2048);
  float* G    = alloc((size_t)HC*HC);
  float* cs   = alloc(HC);
  float* cp   = alloc((size_t)16*HC);
  float* gp1  = alloc((size_t)256*GBLK);
  float* gp2  = alloc((size_t)256*GBLK);
  ushort* w5bf = (ushort*)alloc(262144);     // 1 MB (O5*HC bf16)
  float* Gp   = u;                           // 32 MB, reuses u (dead after layer 4)
  ushort* hbf = (ushort*)s;                  // 33.5 MB, reuses s (dead after layer 4)

  k_transpose<<<(BB*NN)/256, 256, 0, stream>>>(x, xP);

  struct Cfg { const float* xin; int xs, C, O, choff; const float* W; const float* g; const float* bb; };
  Cfg cfg[4] = {
    { xP,    4,   3,   64,   0, W1, g1, b1 },
    { h,     HC,  64,  64,  64, W2, g2, b2 },
    { h+64,  HC,  64, 128, 128, W3, g3, b3 },
    { h+128, HC, 128, 256, 256, W4, g4, b4 },
  };

  int* cur = idxA;
  int* prv = idxB;
  for (int i = 0; i < 4; ++i){
    const Cfg& c = cfg[i];
    k_sqn<<<(BB*NN)/256, 256, 0, stream>>>(c.xin, c.xs, c.C, sqn);
    if (i == 0)           k_knn<3,256,4,false><<<(BB*NN)/16, 256, 0, stream>>>(c.xin, c.xs, sqn, nullptr, cur);
    else if (c.C == 64)   k_knn<64,256,4,true><<<(BB*NN)/16, 256, 0, stream>>>(c.xin, c.xs, sqn, prv, cur);
    else                  k_knn<128,256,4,true><<<(BB*NN)/16, 256, 0, stream>>>(c.xin, c.xs, sqn, prv, cur);
    int OC = c.O * c.C;
    k_wprep<<<(OC + 255)/256, 256, 0, stream>>>(c.W, c.O, c.C, wu, wv);
    k_uv<<<dim3((BB*NN)/64, c.O/64), 256, 0, stream>>>(c.xin, c.xs, c.C, wu, wv, c.O, u, v);
    k_gather<<<GBLK, 256, 0, stream>>>(u, v, cur, c.O, s, gp1, gp2);
    k_pred<<<c.O, 256, 0, stream>>>(gp1, gp2, S1, S2);
    k_fin<<<4, 256, 0, stream>>>(S1, S2, c.g, c.bb, c.O, (float)((size_t)BB*NN*KNNK), Ab, Bb);
    k_bnle<<<((size_t)BB*NN*c.O)/256, 256, 0, stream>>>(s, Ab, Bb, c.O, c.choff, h);
    int* t = cur; cur = prv; prv = t;
  }

  // convert h and W5 to bf16 for the MFMA layer-5 GEMM
  k_h2bf<<<((size_t)BB*NN*HC)/(256*4), 256, 0, stream>>>(h, hbf);
  k_w5cvt<<<((size_t)O5*HC)/(256*4), 256, 0, stream>>>(W5, w5bf);

  // layer 5 stats via covariance: S2 = w^T (h^T h) w, S1 = w . colsum(h)
  k_colsum<<<dim3(8, 16), 256, 0, stream>>>(h, cp);
  k_csred<<<2, 256, 0, stream>>>(cp, cs);
  k_syrk<<<dim3(4, 4, 32), 256, 0, stream>>>(h, Gp);
  k_gred<<<(HC*HC)/256, 256, 0, stream>>>(Gp, G);
  k_quad<<<O5, 256, 0, stream>>>(G, W5, cs, S1, S2);
  k_fin<<<4, 256, 0, stream>>>(S1, S2, g5, b5, O5, (float)((size_t)BB*NN), Ab, Bb);
  k_gemm5m<<<dim3((BB*NN)/128, O5/128), 256, 0, stream>>>(hbf, w5bf, Ab, Bb, mpart, spart);
  k_pool<<<(BB*O5)/256, 256, 0, stream>>>(mpart, spart, pbuf);

  k_final<<<256, 256, 0, stream>>>(pbuf, Wl, g6, b6, out);
}